// Round 5
// baseline (88.451 us; speedup 1.0000x reference)
//
#include <hip/hip_runtime.h>
#include <hip/hip_bf16.h>

// Problem constants (from reference)
#define B_   32
#define N_   64
#define C_   3
#define H_   512
#define W_   512
#define P_   16
#define BAND 16                  // rows per block
#define PLANE (H_ * W_)          // 262144 floats per channel plane
#define IMG   (C_ * PLANE)       // 786432 floats per batch image

typedef float f32x4 __attribute__((ext_vector_type(4)));

// One block = a 16-row band of one image, all 3 channels.
// Wave 0 builds the list of patches intersecting the band (tr in
// [r0-15, r0+15], expected ~4 of 64), then 256 threads stream the band
// image->out as float4s ([C][row][col4] order: each wave = 1KB contiguous),
// adding overlapping patch values in registers. Pure gather, no atomics,
// grid = 1024 blocks = 4/CU fully co-resident.
__global__ __launch_bounds__(256)
void ImagePatch_fused_kernel(const float* __restrict__ image,
                             const float* __restrict__ emb,
                             const int*   __restrict__ labels,
                             const int*   __restrict__ top_left,
                             float*       __restrict__ out) {
    __shared__ int s_cnt;
    __shared__ int s_tr[N_];   // patch top row
    __shared__ int s_tc[N_];   // patch left col
    __shared__ int s_lb[N_];   // label

    const int bid = blockIdx.x;
    const int r0  = (bid & (H_ / BAND - 1)) * BAND;  // band start row
    const int b   = bid >> 5;                        // / (H_/BAND)
    const int tid = threadIdx.x;

    // ---- build band overlap list (wave 0) ----
    if (tid < 64) {
        const int idx = b * N_ + tid;
        const int tr  = top_left[idx * 2];
        const bool cover = (tr + P_ > r0) && (tr < r0 + BAND);
        const unsigned long long m = __ballot(cover);
        if (cover) {
            const int pos = __popcll(m & ((1ull << tid) - 1ull));
            s_tr[pos] = tr;
            s_tc[pos] = top_left[idx * 2 + 1];
            s_lb[pos] = labels[idx];
        }
        if (tid == 0) s_cnt = __popcll(m);
    }
    __syncthreads();

    const int cnt = s_cnt;
    const size_t ibase = (size_t)b * IMG + (size_t)r0 * W_;

    // ---- stream the band: BAND*C*128 float4 slots, 24 per thread ----
    // slot layout: ch (it>>11) | row (it>>7 & 15) | col4 (it & 127)
    for (int it = tid; it < BAND * C_ * (W_ / 4); it += 256) {
        const int col4 = it & 127;
        const int row  = (it >> 7) & (BAND - 1);
        const int ch   = it >> 11;
        const int c0   = col4 * 4;
        const size_t off = ibase + (size_t)ch * PLANE + (size_t)row * W_ + c0;

        f32x4 v = *(const f32x4*)(image + off);

        const int r = r0 + row;
        for (int k = 0; k < cnt; ++k) {
            const unsigned dr = (unsigned)(r - s_tr[k]);
            const int tc = s_tc[k];
            if (dr < P_ && c0 + 3 >= tc && c0 < tc + P_) {
                const float* e = emb + s_lb[k] * (C_ * P_ * P_)
                                     + ch * (P_ * P_) + dr * P_;
                #pragma unroll
                for (int q = 0; q < 4; ++q) {
                    const unsigned dc = (unsigned)(c0 + q - tc);
                    if (dc < P_) v[q] += e[dc];
                }
            }
        }

        *(f32x4*)(out + off) = v;
    }
}

extern "C" void kernel_launch(void* const* d_in, const int* in_sizes, int n_in,
                              void* d_out, int out_size, void* d_ws, size_t ws_size,
                              hipStream_t stream) {
    const float* image    = (const float*)d_in[0];   // [B, 3, H, W]
    const float* emb      = (const float*)d_in[1];   // [128, 768]
    const int*   labels   = (const int*)d_in[2];     // [B, N]
    const int*   top_left = (const int*)d_in[3];     // [B, N, 2]
    float*       out      = (float*)d_out;           // [B, 3, H, W]

    const int grid = B_ * (H_ / BAND);               // 1024 blocks
    ImagePatch_fused_kernel<<<grid, 256, 0, stream>>>(image, emb, labels, top_left, out);
}

// Round 6
// 36.034 us; speedup vs baseline: 2.4546x; 2.4546x over previous
//
#include <hip/hip_runtime.h>
#include <hip/hip_bf16.h>

// Problem constants (from reference)
#define B_   32
#define N_   64
#define C_   3
#define H_   512
#define W_   512
#define P_   16
#define PLANE (H_ * W_)          // 262144 floats per channel plane
#define IMG   (C_ * PLANE)       // 786432 floats per batch image

typedef float f32x4 __attribute__((ext_vector_type(4)));

// Wave-autonomous: one wave = half a row (256 cols) x 3 channels.
// No LDS, no __syncthreads. Each wave ballots the 64 patches of its image
// for row overlap and broadcasts the ~2 hits via one packed __shfl each
// (tr<<16 | tc<<7 | label). Then 3 up-front float4 loads, register adds,
// 3 stores. Pure gather, max occupancy, deep MLP.
__global__ __launch_bounds__(256)
void ImagePatch_fused_kernel(const float* __restrict__ image,
                             const float* __restrict__ emb,
                             const int*   __restrict__ labels,
                             const int*   __restrict__ top_left,
                             float*       __restrict__ out) {
    const int tid  = threadIdx.x;
    const int lane = tid & 63;
    const int gw   = blockIdx.x * 4 + (tid >> 6);   // global wave id
    const int half = gw & 1;
    const int r    = (gw >> 1) & (H_ - 1);
    const int b    = gw >> 10;                      // / (2*H_)

    // ---- per-wave overlap list in registers ----
    const int idx = b * N_ + lane;
    const int tr  = top_left[idx * 2];
    const int tc  = top_left[idx * 2 + 1];
    const int lb  = labels[idx];
    const int pack = (tr << 16) | (tc << 7) | lb;
    unsigned long long m = __ballot((unsigned)(r - tr) < P_);

    // ---- stream: 3 loads up-front, add, 3 stores ----
    const int c0 = lane * 4 + half * 256;
    const size_t base = (size_t)b * IMG + (size_t)r * W_ + c0;

    f32x4 v0 = *(const f32x4*)(image + base);
    f32x4 v1 = *(const f32x4*)(image + base + PLANE);
    f32x4 v2 = *(const f32x4*)(image + base + 2 * PLANE);

    while (m) {
        const int k = __ffsll((unsigned long long)m) - 1;
        m &= m - 1;
        const int pk   = __shfl(pack, k);
        const int tr_k = pk >> 16;
        const int tc_k = (pk >> 7) & 0x1FF;
        const int lb_k = pk & 0x7F;
        const int dr   = r - tr_k;
        if (c0 + 3 >= tc_k && c0 < tc_k + P_) {
            const float* e = emb + lb_k * (C_ * P_ * P_) + dr * P_;
            #pragma unroll
            for (int q = 0; q < 4; ++q) {
                const unsigned dc = (unsigned)(c0 + q - tc_k);
                if (dc < P_) {
                    v0[q] += e[dc];
                    v1[q] += e[P_ * P_ + dc];
                    v2[q] += e[2 * P_ * P_ + dc];
                }
            }
        }
    }

    *(f32x4*)(out + base)             = v0;
    *(f32x4*)(out + base + PLANE)     = v1;
    *(f32x4*)(out + base + 2 * PLANE) = v2;
}

extern "C" void kernel_launch(void* const* d_in, const int* in_sizes, int n_in,
                              void* d_out, int out_size, void* d_ws, size_t ws_size,
                              hipStream_t stream) {
    const float* image    = (const float*)d_in[0];   // [B, 3, H, W]
    const float* emb      = (const float*)d_in[1];   // [128, 768]
    const int*   labels   = (const int*)d_in[2];     // [B, N]
    const int*   top_left = (const int*)d_in[3];     // [B, N, 2]
    float*       out      = (float*)d_out;           // [B, 3, H, W]

    // one wave per half-row: B * H * 2 waves, 4 waves per 256-thread block
    const int grid = B_ * H_ * 2 / 4;                // 8192 blocks
    ImagePatch_fused_kernel<<<grid, 256, 0, stream>>>(image, emb, labels, top_left, out);
}

// Round 7
// 35.612 us; speedup vs baseline: 2.4837x; 1.0118x over previous
//
#include <hip/hip_runtime.h>
#include <hip/hip_bf16.h>

// Problem constants (from reference)
#define B_   32
#define N_   64
#define C_   3
#define H_   512
#define W_   512
#define P_   16
#define PLANE (H_ * W_)          // 262144 floats per channel plane
#define IMG   (C_ * PLANE)       // 786432 floats per batch image

typedef float f32x4 __attribute__((ext_vector_type(4)));

// Wave-autonomous: one wave = half a row (256 cols) x 3 channels.
// No LDS, no __syncthreads. Each wave ballots the 64 patches of its image
// for row overlap and broadcasts the ~2 hits via one packed __shfl each
// (tr<<16 | tc<<7 | label). Then 3 up-front float4 loads, register adds,
// 3 stores.
// Loads are CACHED (image stays L3-resident across replays — profiled
// FETCH showed only ~52MB of 100.7MB coming from HBM). Stores are
// NONTEMPORAL: out is never re-read, so don't let it evict image from L3.
__global__ __launch_bounds__(256)
void ImagePatch_fused_kernel(const float* __restrict__ image,
                             const float* __restrict__ emb,
                             const int*   __restrict__ labels,
                             const int*   __restrict__ top_left,
                             float*       __restrict__ out) {
    const int tid  = threadIdx.x;
    const int lane = tid & 63;
    const int gw   = blockIdx.x * 4 + (tid >> 6);   // global wave id
    const int half = gw & 1;
    const int r    = (gw >> 1) & (H_ - 1);
    const int b    = gw >> 10;                      // / (2*H_)

    // ---- per-wave overlap list in registers ----
    const int idx = b * N_ + lane;
    const int tr  = top_left[idx * 2];
    const int tc  = top_left[idx * 2 + 1];
    const int lb  = labels[idx];
    const int pack = (tr << 16) | (tc << 7) | lb;
    unsigned long long m = __ballot((unsigned)(r - tr) < P_);

    // ---- stream: 3 loads up-front, add, 3 stores ----
    const int c0 = lane * 4 + half * 256;
    const size_t base = (size_t)b * IMG + (size_t)r * W_ + c0;

    f32x4 v0 = *(const f32x4*)(image + base);
    f32x4 v1 = *(const f32x4*)(image + base + PLANE);
    f32x4 v2 = *(const f32x4*)(image + base + 2 * PLANE);

    while (m) {
        const int k = __ffsll((unsigned long long)m) - 1;
        m &= m - 1;
        const int pk   = __shfl(pack, k);
        const int tr_k = pk >> 16;
        const int tc_k = (pk >> 7) & 0x1FF;
        const int lb_k = pk & 0x7F;
        const int dr   = r - tr_k;
        if (c0 + 3 >= tc_k && c0 < tc_k + P_) {
            const float* e = emb + lb_k * (C_ * P_ * P_) + dr * P_;
            #pragma unroll
            for (int q = 0; q < 4; ++q) {
                const unsigned dc = (unsigned)(c0 + q - tc_k);
                if (dc < P_) {
                    v0[q] += e[dc];
                    v1[q] += e[P_ * P_ + dc];
                    v2[q] += e[2 * P_ * P_ + dc];
                }
            }
        }
    }

    __builtin_nontemporal_store(v0, (f32x4*)(out + base));
    __builtin_nontemporal_store(v1, (f32x4*)(out + base + PLANE));
    __builtin_nontemporal_store(v2, (f32x4*)(out + base + 2 * PLANE));
}

extern "C" void kernel_launch(void* const* d_in, const int* in_sizes, int n_in,
                              void* d_out, int out_size, void* d_ws, size_t ws_size,
                              hipStream_t stream) {
    const float* image    = (const float*)d_in[0];   // [B, 3, H, W]
    const float* emb      = (const float*)d_in[1];   // [128, 768]
    const int*   labels   = (const int*)d_in[2];     // [B, N]
    const int*   top_left = (const int*)d_in[3];     // [B, N, 2]
    float*       out      = (float*)d_out;           // [B, 3, H, W]

    // one wave per half-row: B * H * 2 waves, 4 waves per 256-thread block
    const int grid = B_ * H_ * 2 / 4;                // 8192 blocks
    ImagePatch_fused_kernel<<<grid, 256, 0, stream>>>(image, emb, labels, top_left, out);
}